// Round 12
// baseline (153.678 us; speedup 1.0000x reference)
//
#include <hip/hip_runtime.h>

typedef __bf16 bf16x8 __attribute__((ext_vector_type(8)));
typedef float f32x4 __attribute__((ext_vector_type(4)));
typedef unsigned short u16;
typedef unsigned int u32;

__device__ __forceinline__ float bf2f(u16 v) {
    union { unsigned u; float f; } x; x.u = ((unsigned)v) << 16; return x.f;
}
__device__ __forceinline__ u16 f2bf(float f) {
    union { float f; unsigned u; } x; x.f = f;
    unsigned r = x.u + 0x7fffu + ((x.u >> 16) & 1u);
    return (u16)(r >> 16);
}
__device__ __forceinline__ float lo_bf(u32 w) {
    union { unsigned u; float f; } x; x.u = w << 16; return x.f;
}
__device__ __forceinline__ float hi_bf(u32 w) {
    union { unsigned u; float f; } x; x.u = w & 0xffff0000u; return x.f;
}

// Runtime dtype probe (HW-verified r4): f32 buffer -> low u16 of each word is
// mantissa bits -> bf16-exponent ~uniform (~44% >= 0x90); bf16 buffer -> 0 hits.
__device__ __forceinline__ bool probe_is_f32(const void* xp) {
    const unsigned* p = (const unsigned*)xp;
    int hits = 0;
#pragma unroll
    for (int i = 0; i < 32; i++) {
        const unsigned e = (p[i] >> 7) & 0xffu;
        hits += (e >= 0x90u) ? 1 : 0;
    }
    return hits > 3;
}

__device__ __forceinline__ float ld1(const void* p, size_t i, bool isf32) {
    return isf32 ? ((const float*)p)[i] : bf2f(((const u16*)p)[i]);
}

// Async global->LDS DMA, 16B/lane; LDS dest = wave-uniform base + lane*16.
__device__ __forceinline__ void gl2lds16(const void* g, void* l) {
    __builtin_amdgcn_global_load_lds(
        (const __attribute__((address_space(1))) u32*)g,
        (__attribute__((address_space(3))) u32*)l, 16, 0, 0);
}

// One-shot input normalization: everything -> bf16, rpb -> f32 * log2(e).
__global__ __launch_bounds__(256)
void convert_inputs(const void* __restrict__ x, const void* __restrict__ qw,
                    const void* __restrict__ qb, const void* __restrict__ pw,
                    const void* __restrict__ pb, const void* __restrict__ rp,
                    u16* __restrict__ xbf, u16* __restrict__ qwbf,
                    u16* __restrict__ qbbf, u16* __restrict__ pwbf,
                    u16* __restrict__ pbbf, float* __restrict__ rpl2e)
{
    const bool isf32 = probe_is_f32(x);
    const int gid = blockIdx.x * 256 + threadIdx.x;
    const int gsz = gridDim.x * 256;

    struct Seg { const void* s; u16* d; int n; };
    const Seg segs[5] = {{x, xbf, 4194304}, {qw, qwbf, 786432}, {pw, pwbf, 262144},
                         {qb, qbbf, 1536}, {pb, pbbf, 512}};
    for (int t = 0; t < 5; t++) {
        const int n4 = segs[t].n >> 2;
        if (isf32) {
            const f32x4* s = (const f32x4*)segs[t].s;
            for (int i = gid; i < n4; i += gsz) {
                f32x4 v = s[i];
                ushort4 o;
                o.x = f2bf(v[0]); o.y = f2bf(v[1]); o.z = f2bf(v[2]); o.w = f2bf(v[3]);
                *(ushort4*)(segs[t].d + i * 4) = o;
            }
        } else {
            const ushort4* s = (const ushort4*)segs[t].s;
            for (int i = gid; i < n4; i += gsz) *(ushort4*)(segs[t].d + i * 4) = s[i];
        }
    }
    for (int i = gid; i < 63504; i += gsz)
        rpl2e[i] = ld1(rp, i, isf32) * 1.4426950408889634f;
}

// GEMM D = A(MxK) @ W(NoutxK)^T + bias, pure bf16, fp32 accum. BMx128 tile.
// K-loop unrolled x2, two BK=32 LDS buffers per operand, one barrier-pair
// per 64 of K. MODE 0: bias[col], dual-dtype store to d_out.
// MODE 1 (TRANSPOSED QKV): A = qkv_w (rows = channels), W-arg = x (tokens).
//   q,k -> [b][h][t][c] packed ushort4; v -> [b][h][c][t] scalar.
template<int MODE, int BM>
__global__ __launch_bounds__(256, MODE == 1 ? 3 : 4)
void gemm_bt(const u16* __restrict__ A, const u16* __restrict__ W,
             const u16* __restrict__ bias, void* __restrict__ out,
             u16* __restrict__ q_out, u16* __restrict__ k_out, u16* __restrict__ v_out,
             const void* __restrict__ probe, int Nout, int K)
{
    __shared__ __align__(16) u16 As[2][BM * 32];
    __shared__ __align__(16) u16 Ws[2][128 * 32];
    constexpr int RW = BM / 32;            // A-frags per wave

    const int tid  = threadIdx.x;
    const int lane = tid & 63;
    const int wave = tid >> 6;
    const int quad = lane >> 4;
    const int l16  = lane & 15;
    const int m0 = blockIdx.y * BM;
    const int n0 = blockIdx.x * 128;
    const int wm = (wave >> 1) * (BM / 2);
    const int wn = (wave & 1) * 64;

    f32x4 acc[RW][4] = {};

    for (int k0 = 0; k0 < K; k0 += 64) {
        __syncthreads();
        for (int u = 0; u < 2; u++) {
            {
                const u16* g = A + (size_t)(m0 + wave * 16 + (lane >> 2)) * K
                                 + k0 + u * 32 + (lane & 3) * 8;
                u16* l = As[u] + wave * 16 * 32;
                for (int p = 0; p < BM / 64; p++) gl2lds16(g + (size_t)p * 64 * K, l + p * 64 * 32);
            }
            {
                const u16* g = W + (size_t)(n0 + wave * 16 + (lane >> 2)) * K
                                 + k0 + u * 32 + (lane & 3) * 8;
                u16* l = Ws[u] + wave * 16 * 32;
                for (int p = 0; p < 2; p++) gl2lds16(g + (size_t)p * 64 * K, l + p * 64 * 32);
            }
        }
        __syncthreads();

        for (int u = 0; u < 2; u++) {
            bf16x8 af[RW], wf[4];
            for (int i = 0; i < RW; i++)
                af[i] = *(const bf16x8*)(As[u] + (wm + i * 16 + l16) * 32 + quad * 8);
            for (int j = 0; j < 4; j++)
                wf[j] = *(const bf16x8*)(Ws[u] + (wn + j * 16 + l16) * 32 + quad * 8);
            for (int i = 0; i < RW; i++)
                for (int j = 0; j < 4; j++)
                    acc[i][j] = __builtin_amdgcn_mfma_f32_16x16x32_bf16(af[i], wf[j], acc[i][j], 0, 0, 0);
        }
    }

    // D layout per 16x16 tile: row = quad*4 + r, col = l16
    if (MODE == 0) {
        const bool isf32 = probe_is_f32(probe);
        for (int j = 0; j < 4; j++) {
            const int col = n0 + wn + j * 16 + l16;
            const float bv = bf2f(bias[col]);
            for (int i = 0; i < RW; i++) {
                const int rbase = m0 + wm + i * 16 + quad * 4;
                for (int r = 0; r < 4; r++) {
                    const float val = acc[i][j][r] + bv;
                    if (isf32) ((float*)out)[(size_t)(rbase + r) * Nout + col] = val;
                    else       ((u16*)out)[(size_t)(rbase + r) * Nout + col]  = f2bf(val);
                }
            }
        }
    } else {
        const int which = m0 >> 9;       // block-uniform (m0 128-aligned)
        float bv[RW][4];
        for (int i = 0; i < RW; i++) {
            const int row4 = m0 + wm + i * 16 + quad * 4;
            for (int r = 0; r < 4; r++) bv[i][r] = bf2f(bias[row4 + r]);
        }
        for (int j = 0; j < 4; j++) {
            const int tok = n0 + wn + j * 16 + l16;
            const int bi = tok >> 10, t = tok & 1023;
            for (int i = 0; i < RW; i++) {
                const int row4 = m0 + wm + i * 16 + quad * 4;
                const int h = (row4 >> 5) & 15;
                const int c = row4 & 31;
                if (which == 2) {        // v: [b][h][c][t]
                    for (int r = 0; r < 4; r++)
                        v_out[((size_t)(bi * 16 + h) * 32 + c + r) * 1024 + t] =
                            f2bf(acc[i][j][r] + bv[i][r]);
                } else {                 // q,k: [b][h][t][c], 8B packed
                    u16* dst = which ? k_out : q_out;
                    ushort4 pk;
                    pk.x = f2bf(acc[i][j][0] + bv[i][0]);
                    pk.y = f2bf(acc[i][j][1] + bv[i][1]);
                    pk.z = f2bf(acc[i][j][2] + bv[i][2]);
                    pk.w = f2bf(acc[i][j][3] + bv[i][3]);
                    *(ushort4*)(dst + ((size_t)(bi * 16 + h) * 1024 + t) * 32 + c) = pk;
                }
            }
        }
    }
}

// Flash attention, S^T formulation, offset-free softmax, MFMA denominator,
// zero shuffles, XCD-swizzled grid (r11: FETCH 70->12 MB). LDS-issue-bound
// (r11 model: ~402 cyc/kt/wave, bias reads = 186 of it). This round: bias
// staged as bf16 in TWO SHIFTED COPIES biasB[s][row][pos] = row[pos+s]; each
// lane's 4 consecutive values start at parity s=(31-bn)&1 -> position p even
// in copy s -> two ALIGNED b32 reads replace four scalar b32 (32->16/kt/wave).
// bf16 bias: |bias|<=0.09 log2-units -> p rel err ~1e-4, negligible.
// Ps stride 72 (>=64 required; r7's 40 aliased rows). TQ=128/block,
// double-buffered K/V register prefetch, 1 barrier/kt, 4 blocks/CU (37.6 KB).
__global__ __launch_bounds__(256, 4)
void attn(const u16* __restrict__ q, const u16* __restrict__ k,
          const u16* __restrict__ vt, const float* __restrict__ rpl2e,
          u16* __restrict__ o)
{
    __shared__ __align__(16) u16 Ks[2][64 * 40];
    __shared__ __align__(16) u16 Vt[2][32 * 72];
    __shared__ __align__(16) u16 Ps[4][16 * 72];
    __shared__ __align__(16) u16 biasB[2][35 * 64];   // [shift][row][pos]

    const int tid  = threadIdx.x;
    const int lane = tid & 63;
    const int wave = tid >> 6;
    const int quad = lane >> 4;
    const int l16  = lane & 15;

    const int h  = blockIdx.x;   // 16 heads (fastest -> fixes XCD class)
    const int qt = blockIdx.y;   // 8 q-tiles of 128
    const int b  = blockIdx.z;
    const int n0 = qt * 128;
    const size_t base = ((size_t)(b * 16 + h)) * 32768;  // q,k [t][c]; vt [c][t]

    // ---- prologue: bias copies, kt=0 K/V, Q frags from global ----
    {
        const int row0 = 28 - 4 * qt;
        const float* rh = rpl2e + (size_t)h * 3969 + (size_t)row0 * 63;
        for (int s = 0; s < 2; s++)
            for (int idx = tid; idx < 2240; idx += 256) {
                const int row = idx >> 6, pos = idx & 63;
                const int col = pos + s;
                biasB[s][idx] = (col <= 62) ? f2bf(rh[row * 63 + col]) : (u16)0;
            }
    }
    uint4 kreg = *(const uint4*)(k + base + (size_t)(tid >> 2) * 32 + (tid & 3) * 8);
    uint4 vreg = *(const uint4*)(vt + base + (size_t)(tid >> 3) * 1024 + (tid & 7) * 8);
    *(uint4*)(Ks[0] + (tid >> 2) * 40 + (tid & 3) * 8) = kreg;
    *(uint4*)(Vt[0] + (tid >> 3) * 72 + (tid & 7) * 8) = vreg;

    bf16x8 qf[2];
    for (int g = 0; g < 2; g++) {
        union { uint4 u; bf16x8 f; } cv;
        cv.u = *(const uint4*)(q + base + (size_t)(n0 + g * 64 + wave * 16 + l16) * 32 + quad * 8);
        qf[g] = cv.f;
    }
    __syncthreads();

    bf16x8 ones;
    for (int i = 0; i < 8; i++) ones[i] = (__bf16)1.0f;

    // o_acc[g][0..1] = O columns ct*16+l16; o_acc[g][2] = denominator l
    f32x4 o_acc[2][3] = {};
    const int bn = (wave & 1) * 16 + l16;   // n & 31 (group-invariant)
    const int sh = (31 - bn) & 1;           // bias copy selector (lane-constant)
    const u16* bb = biasB[sh];
    const float SC = 0.25503485724582146f;  // d^-0.5 * log2(e)
    u16* pw = Ps[wave];

    for (int kt = 0; kt < 16; kt++) {
        const int cur = kt & 1;
        if (kt < 15) {   // prefetch next K/V tile into regs (in flight during compute)
            const int mn = (kt + 1) * 64;
            kreg = *(const uint4*)(k + base + (size_t)(mn + (tid >> 2)) * 32 + (tid & 3) * 8);
            vreg = *(const uint4*)(vt + base + (size_t)(tid >> 3) * 1024 + mn + (tid & 7) * 8);
        }

        bf16x8 kf[4];
        for (int j = 0; j < 4; j++)
            kf[j] = *(const bf16x8*)(Ks[cur] + (j * 16 + l16) * 40 + quad * 8);
        bf16x8 vf[2][2];                    // V frags: g-invariant, load once
        for (int kc = 0; kc < 2; kc++)
            for (int ct = 0; ct < 2; ct++)
                vf[kc][ct] = *(const bf16x8*)(Vt[cur] + (ct * 16 + l16) * 72 + kc * 32 + quad * 8);

        for (int g = 0; g < 2; g++) {
            // S^T tile: D col n=l16, row m_loc = j*16 + quad*4 + r
            f32x4 s4[4];
            const f32x4 zero = {};
            for (int j = 0; j < 4; j++)
                s4[j] = __builtin_amdgcn_mfma_f32_16x16x32_bf16(kf[j], qf[g], zero, 0, 0, 0);

            const int rbase = 2 * kt - (wave >> 1) - 2 * g + 3;
            for (int j = 0; j < 4; j++) {
                // 4 bias values via two aligned b32 reads from shifted copy
                const int p = (j & 1) * 16 + quad * 4 - bn + 31 - sh;  // even
                const u32* bp = (const u32*)(bb + (rbase + (j >> 1)) * 64 + p);
                const u32 w0 = bp[0], w1 = bp[1];
                const float b0 = lo_bf(w0), b1 = hi_bf(w0);
                const float b2 = lo_bf(w1), b3 = hi_bf(w1);
                ushort4 pk;
                u16* pks = (u16*)&pk;
                {
                    union { __bf16 bf; u16 u; } cv;
                    cv.bf = (__bf16)__builtin_amdgcn_exp2f(s4[j][0] * SC + b0); pks[0] = cv.u;
                    cv.bf = (__bf16)__builtin_amdgcn_exp2f(s4[j][1] * SC + b1); pks[1] = cv.u;
                    cv.bf = (__bf16)__builtin_amdgcn_exp2f(s4[j][2] * SC + b2); pks[2] = cv.u;
                    cv.bf = (__bf16)__builtin_amdgcn_exp2f(s4[j][3] * SC + b3); pks[3] = cv.u;
                }
                // P[n=l16][m = j*16 + quad*4 + r] -> one 8B store
                *(ushort4*)(pw + l16 * 72 + j * 16 + quad * 4) = pk;
            }

            // O += P·V and l += P·1 (in-wave DS ordering covers write->read)
            for (int kc = 0; kc < 2; kc++) {
                const bf16x8 pa = *(const bf16x8*)(pw + l16 * 72 + kc * 32 + quad * 8);
                for (int ct = 0; ct < 2; ct++)
                    o_acc[g][ct] = __builtin_amdgcn_mfma_f32_16x16x32_bf16(pa, vf[kc][ct], o_acc[g][ct], 0, 0, 0);
                o_acc[g][2] = __builtin_amdgcn_mfma_f32_16x16x32_bf16(pa, ones, o_acc[g][2], 0, 0, 0);
            }
        }

        if (kt < 15) {   // write prefetched tile to back buffer
            *(uint4*)(Ks[cur ^ 1] + (tid >> 2) * 40 + (tid & 3) * 8) = kreg;
            *(uint4*)(Vt[cur ^ 1] + (tid >> 3) * 72 + (tid & 7) * 8) = vreg;
        }
        __syncthreads();
    }

    for (int g = 0; g < 2; g++)
        for (int r = 0; r < 4; r++) {
            const float inv = __builtin_amdgcn_rcpf(o_acc[g][2][r]);
            const int n = n0 + g * 64 + wave * 16 + quad * 4 + r;
            u16* orow = o + ((size_t)b * 1024 + n) * 512 + h * 32;
            orow[l16]      = f2bf(o_acc[g][0][r] * inv);
            orow[16 + l16] = f2bf(o_acc[g][1][r] * inv);
        }
}

extern "C" void kernel_launch(void* const* d_in, const int* in_sizes, int n_in,
                              void* d_out, int out_size, void* d_ws, size_t ws_size,
                              hipStream_t stream) {
    const void* x      = d_in[0];  // (8192,512)
    const void* qkv_w  = d_in[1];  // (1536,512)
    const void* qkv_b  = d_in[2];  // (1536)
    const void* rpb    = d_in[3];  // (16,63,63)
    const void* proj_w = d_in[4];  // (512,512)
    const void* proj_b = d_in[5];  // (512)

    // ws layout (u16 units), ~26.3 MiB. xbf aliases ao (disjoint lifetimes).
    // q lives in d_out (consumed by attn before proj GEMM overwrites d_out).
    u16* ws    = (u16*)d_ws;
    u16* kb    = ws;                   // [b][h][t][c]  8 MiB
    u16* vb    = ws + 4194304;         // [b][h][c][t]  8 MiB
    u16* xbf   = ws + 8388608;         // (8192,512)    8 MiB (== ao)
    u16* ao    = xbf;
    u16* qwbf  = ws + 12582912;        // 1.5 MiB
    u16* pwbf  = ws + 13369344;        // 0.5 MiB
    u16* qbbf  = ws + 13631488;
    u16* pbbf  = ws + 13633024;
    float* rpl2e = (float*)(ws + 13633536);  // 254 KiB
    u16* qb    = (u16*)d_out;          // [b][h][t][c]  8 MiB

    convert_inputs<<<1024, 256, 0, stream>>>(x, qkv_w, qkv_b, proj_w, proj_b, rpb,
                                             xbf, qwbf, qbbf, pwbf, pbbf, rpl2e);

    // QKV GEMM, TRANSPOSED: rows = channels (A = qkv_w), cols = tokens (W-arg = x)
    dim3 g1(8192 / 128, 1536 / 128);
    gemm_bt<1, 128><<<g1, 256, 0, stream>>>(qwbf, xbf, qbbf, nullptr, qb, kb, vb, x, 8192, 512);

    // attention: XCD-swizzled grid (x=h fixes XCD class per (b,h))
    dim3 g2(16, 8, 8);
    attn<<<g2, 256, 0, stream>>>(qb, kb, vb, rpl2e, ao);

    dim3 g3(512 / 128, 8192 / 64);
    gemm_bt<0, 64><<<g3, 256, 0, stream>>>(ao, pwbf, pbbf, d_out, nullptr, nullptr, nullptr, x, 512, 512);
}